// Round 6
// baseline (317.011 us; speedup 1.0000x reference)
//
#include <hip/hip_runtime.h>

typedef __bf16 bf16x8 __attribute__((ext_vector_type(8)));
typedef float  f32x4  __attribute__((ext_vector_type(4)));
typedef unsigned int u32x4 __attribute__((ext_vector_type(4)));

#define MFMA16 __builtin_amdgcn_mfma_f32_16x16x32_bf16

// ---- LDS layout ----
// unsigned short indices:
#define XT_S 0        // Xt[60][40] bf16 (cols 30..39 zero)
#define A_S  2400     // A[60][72] bf16 (cols 60..63 zero, 64..71 unused)
#define B_S  6720     // B[60][72] bf16
#define HT_S 11040    // 4 waves * [16][72] bf16
// float indices (short idx / 2):
#define EB_F 7824     // Ebar[60][20] f32
#define O_F  9024     // O[24] f32
#define NSH  18096    // total shorts = 36192 B (35.3 KB -> 4 blocks/CU)

__device__ __forceinline__ float bl(unsigned u){ return __builtin_bit_cast(float, u << 16); }
__device__ __forceinline__ float bh(unsigned u){ return __builtin_bit_cast(float, u & 0xffff0000u); }
__device__ __forceinline__ unsigned short bits16(float x){ return __builtin_bit_cast(unsigned short, (__bf16)x); }

__device__ __forceinline__ bf16x8 addrelu(u32x4 a, u32x4 b){
    bf16x8 o;
    #pragma unroll
    for (int k = 0; k < 4; ++k){
        const float lo = bl(a[k]) + bl(b[k]);
        const float hi = bh(a[k]) + bh(b[k]);
        o[2*k]   = (__bf16)fmaxf(lo, 0.f);
        o[2*k+1] = (__bf16)fmaxf(hi, 0.f);
    }
    return o;
}

__global__ __launch_bounds__(256)
__attribute__((amdgpu_waves_per_eu(4, 4)))
void innet_kernel(const float* __restrict__ x,
                  const float* __restrict__ fr_w1, const float* __restrict__ fr_b1,
                  const float* __restrict__ fr_w2, const float* __restrict__ fr_b2,
                  const float* __restrict__ fr_w3, const float* __restrict__ fr_b3,
                  const float* __restrict__ fo_w1, const float* __restrict__ fo_b1,
                  const float* __restrict__ fo_w2, const float* __restrict__ fo_b2,
                  const float* __restrict__ fo_w3, const float* __restrict__ fo_b3,
                  float* __restrict__ out)
{
    __shared__ __align__(16) unsigned short ss[NSH];
    float* sf = (float*)ss;

    const int b      = blockIdx.x;
    const int tid    = threadIdx.x;
    const int lane15 = tid & 15;
    const int g4     = (tid >> 4) & 3;
    const int w      = tid >> 6;
    const int wbS    = HT_S + w * 1152;      // per-wave Ht base (short idx)

    // ---- phase 0: stage x -> Xt bf16 [p][f], zero pads/EB/O ----
    const float* xb = x + b * 1800;
    for (int i = tid; i < 1800; i += 256){
        const int f = i / 60, p = i - f * 60;
        ss[XT_S + p * 40 + f] = bits16(xb[i]);
    }
    for (int i = tid; i < 600; i += 256){
        const int p = i / 10;
        ss[XT_S + p * 40 + 30 + (i - p * 10)] = 0;
    }
    for (int i = tid; i < 1200; i += 256) sf[EB_F + i] = 0.f;
    if (tid < 24) sf[O_F + tid] = 0.f;
    __syncthreads();

    // ---- phase 1: A/B panels via MFMA. wave w = M-tile rows [16w,16w+16) ----
    {
        bf16x8 w1af[4], w1bf[4];
        float b1v[4];
        #pragma unroll
        for (int n = 0; n < 4; ++n){
            const int col = n * 16 + lane15;
            const bool cvv = col < 60;
            b1v[n] = cvv ? fr_b1[col] : 0.f;
            #pragma unroll
            for (int j = 0; j < 8; ++j){
                const int f = g4 * 8 + j;
                w1af[n][j] = (__bf16)((f < 30 && cvv) ? fr_w1[f * 60 + col] : 0.f);
                w1bf[n][j] = (__bf16)((f < 30 && cvv) ? fr_w1[(30 + f) * 60 + col] : 0.f);
            }
        }
        const int pr_ = w * 16 + lane15;
        const u32x4 ux = *(const u32x4*)&ss[XT_S + pr_ * 40 + g4 * 8];
        const bf16x8 xa = __builtin_bit_cast(bf16x8, ux);
        const f32x4 z = {0.f, 0.f, 0.f, 0.f};
        f32x4 aA0 = MFMA16(xa, w1af[0], z, 0, 0, 0);
        f32x4 aA1 = MFMA16(xa, w1af[1], z, 0, 0, 0);
        f32x4 aA2 = MFMA16(xa, w1af[2], z, 0, 0, 0);
        f32x4 aA3 = MFMA16(xa, w1af[3], z, 0, 0, 0);
        f32x4 aB0 = MFMA16(xa, w1bf[0], z, 0, 0, 0);
        f32x4 aB1 = MFMA16(xa, w1bf[1], z, 0, 0, 0);
        f32x4 aB2 = MFMA16(xa, w1bf[2], z, 0, 0, 0);
        f32x4 aB3 = MFMA16(xa, w1bf[3], z, 0, 0, 0);
        #pragma unroll
        for (int reg = 0; reg < 4; ++reg){
            const int p = w * 16 + g4 * 4 + reg;
            if (p < 60){
                ss[A_S + p * 72 +      lane15] = bits16(aA0[reg] + b1v[0]);
                ss[A_S + p * 72 + 16 + lane15] = bits16(aA1[reg] + b1v[1]);
                ss[A_S + p * 72 + 32 + lane15] = bits16(aA2[reg] + b1v[2]);
                ss[A_S + p * 72 + 48 + lane15] = bits16(aA3[reg] + b1v[3]);
                ss[B_S + p * 72 +      lane15] = bits16(aB0[reg]);
                ss[B_S + p * 72 + 16 + lane15] = bits16(aB1[reg]);
                ss[B_S + p * 72 + 32 + lane15] = bits16(aB2[reg]);
                ss[B_S + p * 72 + 48 + lane15] = bits16(aB3[reg]);
            }
        }
    }
    __syncthreads();

    // ---- fr layer-2/3 weight fragments (registers) ----
    bf16x8 w2f[4][2], w3f[2][2];
    float b2v[4], b3v[2];
    #pragma unroll
    for (int n = 0; n < 4; ++n){
        const int col = n * 16 + lane15;
        b2v[n] = (col < 60) ? fr_b2[col] : 0.f;
        #pragma unroll
        for (int c = 0; c < 2; ++c){
            #pragma unroll
            for (int j = 0; j < 8; ++j){
                const int k = c * 32 + g4 * 8 + j;
                w2f[n][c][j] = (__bf16)((k < 60 && col < 60) ? fr_w2[k * 60 + col] : 0.f);
            }
        }
    }
    #pragma unroll
    for (int n = 0; n < 2; ++n){
        const int col = n * 16 + lane15;
        b3v[n] = (col < 20) ? fr_b3[col] : 0.f;
        #pragma unroll
        for (int c = 0; c < 2; ++c){
            #pragma unroll
            for (int j = 0; j < 8; ++j){
                const int k = c * 32 + g4 * 8 + j;
                w3f[n][c][j] = (__bf16)((k < 60 && col < 20) ? fr_w3[k * 20 + col] : 0.f);
            }
        }
    }

    auto writeHt = [&](const f32x4& a, float bias, int n){
        #pragma unroll
        for (int reg = 0; reg < 4; ++reg)
            ss[wbS + (g4 * 4 + reg) * 72 + n * 16 + lane15] = bits16(fmaxf(a[reg] + bias, 0.f));
    };
    auto scat = [&](const f32x4& ae, int n, int q0){
        const int col = n * 16 + lane15;
        const bool cv = (col < 20);
        float run = 0.f;
        int pr = (q0 + g4 * 4) / 60;
        #pragma unroll
        for (int reg = 0; reg < 4; ++reg){
            const int qq = q0 + g4 * 4 + reg;
            const int rr = qq / 60;
            const int si = qq - rr * 60;
            float e = 0.f;
            if (cv && si != rr) e = fmaxf(ae[reg] + b3v[n], 0.f);
            if (rr != pr){
                if (cv && run != 0.f) atomicAdd(&sf[EB_F + pr * 20 + col], run);
                run = 0.f; pr = rr;
            }
            run += e;
        }
        if (cv && run != 0.f) atomicAdd(&sf[EB_F + pr * 20 + col], run);
    };

    // ---- phase 2: pair loop over 225 16-row tiles of the 60x60 grid ----
    #pragma unroll 1
    for (int t = w; t < 225; t += 4){
        const int q0 = t * 16;
        const int q  = q0 + lane15;
        const int r  = q / 60;
        const int si = q - r * 60;
        const int ba = A_S + r  * 72 + g4 * 8;
        const int bb = B_S + si * 72 + g4 * 8;
        const u32x4 ra0 = *(const u32x4*)&ss[ba];
        const u32x4 rb0 = *(const u32x4*)&ss[bb];
        const u32x4 ra1 = *(const u32x4*)&ss[ba + 32];
        const u32x4 rb1 = *(const u32x4*)&ss[bb + 32];
        const bf16x8 af0 = addrelu(ra0, rb0);
        const bf16x8 af1 = addrelu(ra1, rb1);

        f32x4 acc0 = {0.f,0.f,0.f,0.f}, acc1 = {0.f,0.f,0.f,0.f};
        f32x4 acc2 = {0.f,0.f,0.f,0.f}, acc3 = {0.f,0.f,0.f,0.f};
        acc0 = MFMA16(af0, w2f[0][0], acc0, 0, 0, 0);
        acc1 = MFMA16(af0, w2f[1][0], acc1, 0, 0, 0);
        acc2 = MFMA16(af0, w2f[2][0], acc2, 0, 0, 0);
        acc3 = MFMA16(af0, w2f[3][0], acc3, 0, 0, 0);
        acc0 = MFMA16(af1, w2f[0][1], acc0, 0, 0, 0);
        acc1 = MFMA16(af1, w2f[1][1], acc1, 0, 0, 0);
        acc2 = MFMA16(af1, w2f[2][1], acc2, 0, 0, 0);
        acc3 = MFMA16(af1, w2f[3][1], acc3, 0, 0, 0);

        writeHt(acc0, b2v[0], 0);
        writeHt(acc1, b2v[1], 1);
        writeHt(acc2, b2v[2], 2);
        writeHt(acc3, b2v[3], 3);
        asm volatile("s_waitcnt lgkmcnt(0)" ::: "memory");
        __builtin_amdgcn_sched_barrier(0);

        const u32x4 h0 = *(const u32x4*)&ss[wbS + lane15 * 72 + g4 * 8];
        const u32x4 h1 = *(const u32x4*)&ss[wbS + lane15 * 72 + 32 + g4 * 8];
        const bf16x8 hf0 = __builtin_bit_cast(bf16x8, h0);
        const bf16x8 hf1 = __builtin_bit_cast(bf16x8, h1);
        f32x4 ae0 = {0.f,0.f,0.f,0.f}, ae1 = {0.f,0.f,0.f,0.f};
        ae0 = MFMA16(hf0, w3f[0][0], ae0, 0, 0, 0);
        ae1 = MFMA16(hf0, w3f[1][0], ae1, 0, 0, 0);
        ae0 = MFMA16(hf1, w3f[0][1], ae0, 0, 0, 0);
        ae1 = MFMA16(hf1, w3f[1][1], ae1, 0, 0, 0);

        scat(ae0, 0, q0);
        scat(ae1, 1, q0);
    }
    __syncthreads();

    // ---- phase 5: output MLP via MFMA. wave w = particle rows [16w,16w+16) ----
    {
        const int p5 = w * 16 + lane15;
        const int pe = (p5 < 60) ? p5 : 0;
        // A-frag for C = [x_p(30), Ebar_p(20)] padded to 64
        const u32x4 uc0 = *(const u32x4*)&ss[XT_S + pe * 40 + g4 * 8];
        bf16x8 ca0 = __builtin_bit_cast(bf16x8, uc0);
        if (g4 == 3){
            ca0[6] = (__bf16)sf[EB_F + pe * 20 + 0];
            ca0[7] = (__bf16)sf[EB_F + pe * 20 + 1];
        }
        bf16x8 ca1;
        #pragma unroll
        for (int j = 0; j < 8; ++j){
            const int d = 2 + g4 * 8 + j;
            ca1[j] = (d < 20) ? (__bf16)sf[EB_F + pe * 20 + d] : (__bf16)0.f;
        }
        // fo_w1 frags
        bf16x8 wf[4][2]; float bv[4];
        #pragma unroll
        for (int n = 0; n < 4; ++n){
            const int col = n * 16 + lane15;
            bv[n] = (col < 60) ? fo_b1[col] : 0.f;
            #pragma unroll
            for (int c = 0; c < 2; ++c){
                #pragma unroll
                for (int j = 0; j < 8; ++j){
                    const int k = c * 32 + g4 * 8 + j;
                    wf[n][c][j] = (__bf16)((k < 50 && col < 60) ? fo_w1[k * 60 + col] : 0.f);
                }
            }
        }
        f32x4 g0 = {0.f,0.f,0.f,0.f}, g1 = {0.f,0.f,0.f,0.f};
        f32x4 g2 = {0.f,0.f,0.f,0.f}, g3 = {0.f,0.f,0.f,0.f};
        g0 = MFMA16(ca0, wf[0][0], g0, 0, 0, 0);
        g1 = MFMA16(ca0, wf[1][0], g1, 0, 0, 0);
        g2 = MFMA16(ca0, wf[2][0], g2, 0, 0, 0);
        g3 = MFMA16(ca0, wf[3][0], g3, 0, 0, 0);
        g0 = MFMA16(ca1, wf[0][1], g0, 0, 0, 0);
        g1 = MFMA16(ca1, wf[1][1], g1, 0, 0, 0);
        g2 = MFMA16(ca1, wf[2][1], g2, 0, 0, 0);
        g3 = MFMA16(ca1, wf[3][1], g3, 0, 0, 0);
        writeHt(g0, bv[0], 0); writeHt(g1, bv[1], 1);
        writeHt(g2, bv[2], 2); writeHt(g3, bv[3], 3);
        asm volatile("s_waitcnt lgkmcnt(0)" ::: "memory");
        __builtin_amdgcn_sched_barrier(0);
        {
            const u32x4 h0 = *(const u32x4*)&ss[wbS + lane15 * 72 + g4 * 8];
            const u32x4 h1 = *(const u32x4*)&ss[wbS + lane15 * 72 + 32 + g4 * 8];
            const bf16x8 hf0 = __builtin_bit_cast(bf16x8, h0);
            const bf16x8 hf1 = __builtin_bit_cast(bf16x8, h1);
            // fo_w2 frags (reuse wf)
            #pragma unroll
            for (int n = 0; n < 4; ++n){
                const int col = n * 16 + lane15;
                bv[n] = (col < 60) ? fo_b2[col] : 0.f;
                #pragma unroll
                for (int c = 0; c < 2; ++c){
                    #pragma unroll
                    for (int j = 0; j < 8; ++j){
                        const int k = c * 32 + g4 * 8 + j;
                        wf[n][c][j] = (__bf16)((k < 60 && col < 60) ? fo_w2[k * 60 + col] : 0.f);
                    }
                }
            }
            g0 = (f32x4){0.f,0.f,0.f,0.f}; g1 = (f32x4){0.f,0.f,0.f,0.f};
            g2 = (f32x4){0.f,0.f,0.f,0.f}; g3 = (f32x4){0.f,0.f,0.f,0.f};
            g0 = MFMA16(hf0, wf[0][0], g0, 0, 0, 0);
            g1 = MFMA16(hf0, wf[1][0], g1, 0, 0, 0);
            g2 = MFMA16(hf0, wf[2][0], g2, 0, 0, 0);
            g3 = MFMA16(hf0, wf[3][0], g3, 0, 0, 0);
            g0 = MFMA16(hf1, wf[0][1], g0, 0, 0, 0);
            g1 = MFMA16(hf1, wf[1][1], g1, 0, 0, 0);
            g2 = MFMA16(hf1, wf[2][1], g2, 0, 0, 0);
            g3 = MFMA16(hf1, wf[3][1], g3, 0, 0, 0);
            writeHt(g0, bv[0], 0); writeHt(g1, bv[1], 1);
            writeHt(g2, bv[2], 2); writeHt(g3, bv[3], 3);
        }
        asm volatile("s_waitcnt lgkmcnt(0)" ::: "memory");
        __builtin_amdgcn_sched_barrier(0);
        {
            const u32x4 h0 = *(const u32x4*)&ss[wbS + lane15 * 72 + g4 * 8];
            const u32x4 h1 = *(const u32x4*)&ss[wbS + lane15 * 72 + 32 + g4 * 8];
            const bf16x8 hf0 = __builtin_bit_cast(bf16x8, h0);
            const bf16x8 hf1 = __builtin_bit_cast(bf16x8, h1);
            // fo_w3 frags (24 cols -> 2 N-tiles)
            bf16x8 w3o[2][2]; float bv3[2];
            #pragma unroll
            for (int n = 0; n < 2; ++n){
                const int col = n * 16 + lane15;
                bv3[n] = (col < 24) ? fo_b3[col] : 0.f;
                #pragma unroll
                for (int c = 0; c < 2; ++c){
                    #pragma unroll
                    for (int j = 0; j < 8; ++j){
                        const int k = c * 32 + g4 * 8 + j;
                        w3o[n][c][j] = (__bf16)((k < 60 && col < 24) ? fo_w3[k * 24 + col] : 0.f);
                    }
                }
            }
            f32x4 o0 = {0.f,0.f,0.f,0.f}, o1 = {0.f,0.f,0.f,0.f};
            o0 = MFMA16(hf0, w3o[0][0], o0, 0, 0, 0);
            o1 = MFMA16(hf0, w3o[1][0], o1, 0, 0, 0);
            o0 = MFMA16(hf1, w3o[0][1], o0, 0, 0, 0);
            o1 = MFMA16(hf1, w3o[1][1], o1, 0, 0, 0);
            #pragma unroll
            for (int n = 0; n < 2; ++n){
                const f32x4 on = (n == 0) ? o0 : o1;
                float ssum = 0.f;
                #pragma unroll
                for (int reg = 0; reg < 4; ++reg){
                    const int p = w * 16 + g4 * 4 + reg;
                    if (p < 60) ssum += fmaxf(on[reg] + bv3[n], 0.f);
                }
                ssum += __shfl_xor(ssum, 16);
                ssum += __shfl_xor(ssum, 32);
                if (g4 == 0){
                    const int col = n * 16 + lane15;
                    if (col < 24) atomicAdd(&sf[O_F + col], ssum);
                }
            }
        }
    }
    __syncthreads();
    if (tid < 24) out[(size_t)b * 24 + tid] = sf[O_F + tid];
}

extern "C" void kernel_launch(void* const* d_in, const int* in_sizes, int n_in,
                              void* d_out, int out_size, void* d_ws, size_t ws_size,
                              hipStream_t stream) {
    const float* x      = (const float*)d_in[0];
    const float* fr_w1  = (const float*)d_in[1];
    const float* fr_b1  = (const float*)d_in[2];
    const float* fr_w2  = (const float*)d_in[3];
    const float* fr_b2  = (const float*)d_in[4];
    const float* fr_w3  = (const float*)d_in[5];
    const float* fr_b3  = (const float*)d_in[6];
    const float* fo_w1  = (const float*)d_in[7];
    const float* fo_b1  = (const float*)d_in[8];
    const float* fo_w2  = (const float*)d_in[9];
    const float* fo_b2  = (const float*)d_in[10];
    const float* fo_w3  = (const float*)d_in[11];
    const float* fo_b3  = (const float*)d_in[12];
    float* out = (float*)d_out;

    const int B = in_sizes[0] / 1800;
    innet_kernel<<<dim3(B), dim3(256), 0, stream>>>(
        x, fr_w1, fr_b1, fr_w2, fr_b2, fr_w3, fr_b3,
        fo_w1, fo_b1, fo_w2, fo_b2, fo_w3, fo_b3, out);
}